// Round 1
// baseline (1642.118 us; speedup 1.0000x reference)
//
#include <hip/hip_runtime.h>
#include <math.h>

#define L 12
#define B 8
#define H 16
#define D 64
#define E 1024
#define F 4096
#define V 50257
#define T 1023
#define NC 8       // key chunks per (b,h)
#define CHK 128    // keys per chunk; NC*CHK = 1024 = T+1

// workspace layout (floats)
#define WS_HA    0
#define WS_HB    (WS_HA + B*E)          // 8192
#define WS_QKV   (WS_HB + B*E)          // 16384
#define WS_M1    (WS_QKV + B*3*E)       // 40960
#define WS_PM    (WS_M1 + B*F)          // 73728
#define WS_PL    (WS_PM + B*H*NC)       // 74752
#define WS_PCTX  (WS_PL + B*H*NC)       // 75776
#define WS_GSUM  (WS_PCTX + B*H*NC*D)   // 141312

// ---- block-redundant LayerNorm stats: wave w handles batch w (BT=512) ----
__device__ __forceinline__ void ln_stats512(const float* __restrict__ h,
                                            float* smean, float* srstd) {
  int w = threadIdx.x >> 6, lane = threadIdx.x & 63;
  const float* hb = h + w * E;
  float s = 0.f;
  for (int i = lane; i < E; i += 64) s += hb[i];
#pragma unroll
  for (int o = 32; o; o >>= 1) s += __shfl_down(s, o);
  float m = __shfl(s, 0) * (1.f / E);
  float s2 = 0.f;
  for (int i = lane; i < E; i += 64) { float d = hb[i] - m; s2 += d * d; }
#pragma unroll
  for (int o = 32; o; o >>= 1) s2 += __shfl_down(s2, o);
  if (lane == 0) {
    smean[w] = m;
    srstd[w] = rsqrtf(__shfl(s2, 0) * (1.f / E) + 1e-5f);
  }
}

// ---- embedding + zero-init of accumulator buffers ----
__global__ __launch_bounds__(256) void k_embed(const int* __restrict__ ids,
    const float* __restrict__ wte, const float* __restrict__ wpe,
    float* __restrict__ hA, float* __restrict__ hB, float* __restrict__ qkv,
    float* __restrict__ m1, float* __restrict__ gsum) {
  int i = blockIdx.x * 256 + threadIdx.x;    // grid 128 -> 32768 threads
  if (i < B * E) {
    int b = i >> 10, e = i & 1023;
    int id = ids[b * 1024 + 1023];           // last token
    hA[i] = wte[(size_t)id * E + e] + wpe[1023 * E + e];
    hB[i] = 0.f;
  }
  if (i < B * 3 * E) qkv[i] = 0.f;
  if (i < B * F) m1[i] = 0.f;
  if (i < B) gsum[i] = 0.f;
}

// ---- LN1 + QKV gemv (48 col-strips x 8 e-slices = 384 blocks) ----
__global__ __launch_bounds__(512) void k_qkv(const float* __restrict__ hA,
    const float* __restrict__ l1w, const float* __restrict__ l1b,
    const float* __restrict__ W, const float* __restrict__ bias,
    float* __restrict__ qkv, float* __restrict__ m1, float* __restrict__ hB) {
  __shared__ float smean[B], srstd[B];
  __shared__ float sx[B][128];
  __shared__ float red[8][B][64];
  int t = threadIdx.x;
  ln_stats512(hA, smean, srstd);
  __syncthreads();
  int strip = blockIdx.x >> 3, slice = blockIdx.x & 7;
  for (int i = t; i < B * 128; i += 512) {
    int b = i >> 7, el = i & 127, e = slice * 128 + el;
    sx[b][el] = (hA[b * E + e] - smean[b]) * srstd[b] * l1w[e] + l1b[e];
  }
  __syncthreads();
  int cl = t & 63, esub = t >> 6;            // 8 subs x 16 e
  int col = strip * 64 + cl;
  float acc[8] = {0.f};
  const float* Wp = W + (size_t)(slice * 128 + esub * 16) * (3 * E) + col;
#pragma unroll 4
  for (int ei = 0; ei < 16; ei++) {
    float w = Wp[(size_t)ei * (3 * E)];
    int el = esub * 16 + ei;
#pragma unroll
    for (int b = 0; b < 8; b++) acc[b] += sx[b][el] * w;
  }
#pragma unroll
  for (int b = 0; b < 8; b++) red[esub][b][cl] = acc[b];
  __syncthreads();
  {
    int b = t >> 6;
    float v = 0.f;
#pragma unroll
    for (int s = 0; s < 8; s++) v += red[s][b][cl];
    int c = strip * 64 + cl;
    if (slice == 0) v += bias[c];
    atomicAdd(&qkv[b * (3 * E) + c], v);
  }
  // tail: zero m1 and hB for this layer's later phases
  for (int i = blockIdx.x * 512 + t; i < B * F + B * E; i += gridDim.x * 512) {
    if (i < B * F) m1[i] = 0.f; else hB[i - B * F] = 0.f;
  }
}

// ---- flash-decode attention partials: block = (b,h,chunk), grid 1024 ----
__global__ __launch_bounds__(512) void k_attn(const float* __restrict__ kc,
    const float* __restrict__ vc, const float* __restrict__ qkv,
    float* __restrict__ pm, float* __restrict__ pl, float* __restrict__ pctx) {
  __shared__ float sq[D];
  __shared__ float ss[CHK];
  __shared__ float sred[8][D];
  __shared__ float sM, sL;
  int t = threadIdx.x;
  int b = blockIdx.x >> 7, h = (blockIdx.x >> 3) & 15, c = blockIdx.x & 7;
  if (t < D) sq[t] = qkv[b * (3 * E) + h * D + t];
  __syncthreads();
  const float* Kc = kc + ((size_t)(b * H + h) * T + c * CHK) * D;
  {
    int k = t >> 2, dsub = t & 3;            // 4 threads/key, 16 d each
    int kg = c * CHK + k;
    const float* krow = (kg < T) ? (Kc + (size_t)k * D)
                                 : (qkv + b * (3 * E) + E + h * D);
    float s = 0.f;
#pragma unroll
    for (int i = 0; i < 16; i += 4) {
      float4 w = *(const float4*)(krow + dsub * 16 + i);
      float4 q = *(const float4*)(&sq[dsub * 16 + i]);
      s += w.x * q.x + w.y * q.y + w.z * q.z + w.w * q.w;
    }
    s += __shfl_xor(s, 1);
    s += __shfl_xor(s, 2);
    if (dsub == 0) ss[k] = s * 0.125f;       // 1/sqrt(64)
  }
  __syncthreads();
  if (t < 64) {
    float m = fmaxf(ss[t], ss[t + 64]);
#pragma unroll
    for (int o = 32; o; o >>= 1) m = fmaxf(m, __shfl_down(m, o));
    if (t == 0) sM = m;
  }
  __syncthreads();
  if (t < CHK) ss[t] = expf(ss[t] - sM);
  __syncthreads();
  if (t < 64) {
    float v = ss[t] + ss[t + 64];
#pragma unroll
    for (int o = 32; o; o >>= 1) v += __shfl_down(v, o);
    if (t == 0) sL = v;
  }
  const float* Vc = vc + ((size_t)(b * H + h) * T + c * CHK) * D;
  {
    int d = t & 63, ksub = t >> 6;           // 8 subs x 16 keys
    float a = 0.f;
#pragma unroll 4
    for (int kk = 0; kk < 16; kk++) {
      int k = ksub * 16 + kk;
      int kg = c * CHK + k;
      const float* vrow = (kg < T) ? (Vc + (size_t)k * D)
                                   : (qkv + b * (3 * E) + 2 * E + h * D);
      a += ss[k] * vrow[d];
    }
    sred[ksub][d] = a;
  }
  __syncthreads();
  int idx = (b * H + h) * NC + c;
  if (t < D) {
    float v = 0.f;
#pragma unroll
    for (int s = 0; s < 8; s++) v += sred[s][t];
    pctx[idx * D + t] = v;
  }
  if (t == 0) { pm[idx] = sM; pl[idx] = sL; }
}

// ---- combine partials + attn-proj + residual: block=(strip,head), grid 256 ----
__global__ __launch_bounds__(512) void k_proj(const float* __restrict__ hA,
    const float* __restrict__ W, const float* __restrict__ bias,
    const float* __restrict__ pm, const float* __restrict__ pl,
    const float* __restrict__ pctx, float* __restrict__ hB) {
  __shared__ float sctx[B][D];
  __shared__ float red[8][B][64];
  int t = threadIdx.x;
  int strip = blockIdx.x >> 4, h = blockIdx.x & 15;
  {
    int b = t >> 6, d = t & 63;
    int base = (b * H + h) * NC;
    float M = -1e30f;
#pragma unroll
    for (int c = 0; c < NC; c++) M = fmaxf(M, pm[base + c]);
    float Ls = 0.f, num = 0.f;
#pragma unroll
    for (int c = 0; c < NC; c++) {
      float w = expf(pm[base + c] - M);
      Ls += w * pl[base + c];
      num += w * pctx[(base + c) * D + d];
    }
    sctx[b][d] = num / Ls;
  }
  __syncthreads();
  int cl = t & 63, esub = t >> 6;            // 8 subs x 8 e (head dims)
  int col = strip * 64 + cl;
  float acc[8] = {0.f};
  const float* Wp = W + (size_t)(h * D + esub * 8) * E + col;
#pragma unroll
  for (int ei = 0; ei < 8; ei++) {
    float w = Wp[(size_t)ei * E];
#pragma unroll
    for (int b = 0; b < 8; b++) acc[b] += sctx[b][esub * 8 + ei] * w;
  }
#pragma unroll
  for (int b = 0; b < 8; b++) red[esub][b][cl] = acc[b];
  __syncthreads();
  {
    int b = t >> 6;
    float v = 0.f;
#pragma unroll
    for (int s = 0; s < 8; s++) v += red[s][b][cl];
    int c2 = strip * 64 + cl;
    if (h == 0) v += hA[b * E + c2] + bias[c2];
    atomicAdd(&hB[b * E + c2], v);
  }
}

// ---- LN2 + FC gemv (64 strips x 8 slices = 512 blocks) ----
__global__ __launch_bounds__(512) void k_fc(const float* __restrict__ hB,
    const float* __restrict__ l2w, const float* __restrict__ l2b,
    const float* __restrict__ W, const float* __restrict__ bias,
    float* __restrict__ m1, float* __restrict__ hA, float* __restrict__ qkv) {
  __shared__ float smean[B], srstd[B];
  __shared__ float sx[B][128];
  __shared__ float red[8][B][64];
  int t = threadIdx.x;
  ln_stats512(hB, smean, srstd);
  __syncthreads();
  int strip = blockIdx.x >> 3, slice = blockIdx.x & 7;
  for (int i = t; i < B * 128; i += 512) {
    int b = i >> 7, el = i & 127, e = slice * 128 + el;
    sx[b][el] = (hB[b * E + e] - smean[b]) * srstd[b] * l2w[e] + l2b[e];
  }
  __syncthreads();
  int cl = t & 63, esub = t >> 6;
  int col = strip * 64 + cl;
  float acc[8] = {0.f};
  const float* Wp = W + (size_t)(slice * 128 + esub * 16) * F + col;
#pragma unroll 4
  for (int ei = 0; ei < 16; ei++) {
    float w = Wp[(size_t)ei * F];
    int el = esub * 16 + ei;
#pragma unroll
    for (int b = 0; b < 8; b++) acc[b] += sx[b][el] * w;
  }
#pragma unroll
  for (int b = 0; b < 8; b++) red[esub][b][cl] = acc[b];
  __syncthreads();
  {
    int b = t >> 6;
    float v = 0.f;
#pragma unroll
    for (int s = 0; s < 8; s++) v += red[s][b][cl];
    int c2 = strip * 64 + cl;
    if (slice == 0) v += bias[c2];
    atomicAdd(&m1[b * F + c2], v);
  }
  // tail: zero hA (next accumulator) and qkv (next layer)
  for (int i = blockIdx.x * 512 + t; i < B * E + B * 3 * E; i += gridDim.x * 512) {
    if (i < B * E) hA[i] = 0.f; else qkv[i - B * E] = 0.f;
  }
}

// ---- gelu + MLP-proj gemv + residual (16 strips x 32 slices = 512 blocks) ----
__global__ __launch_bounds__(512) void k_mlp(const float* __restrict__ m1,
    const float* __restrict__ W, const float* __restrict__ bias,
    const float* __restrict__ hB, float* __restrict__ hA) {
  __shared__ float sg[B][128];
  __shared__ float red[8][B][64];
  int t = threadIdx.x;
  int strip = blockIdx.x >> 5, slice = blockIdx.x & 31;
  for (int i = t; i < B * 128; i += 512) {
    int b = i >> 7, fl = i & 127, f = slice * 128 + fl;
    float x = m1[b * F + f];
    float th = tanhf(0.7978845608028654f * (x + 0.044715f * x * x * x));
    sg[b][fl] = 0.5f * x * (1.f + th);
  }
  __syncthreads();
  int cl = t & 63, fsub = t >> 6;
  int col = strip * 64 + cl;
  float acc[8] = {0.f};
  const float* Wp = W + (size_t)(slice * 128 + fsub * 16) * E + col;
#pragma unroll 4
  for (int fi = 0; fi < 16; fi++) {
    float w = Wp[(size_t)fi * E];
    int fl = fsub * 16 + fi;
#pragma unroll
    for (int b = 0; b < 8; b++) acc[b] += sg[b][fl] * w;
  }
#pragma unroll
  for (int b = 0; b < 8; b++) red[fsub][b][cl] = acc[b];
  __syncthreads();
  {
    int b = t >> 6;
    float v = 0.f;
#pragma unroll
    for (int s = 0; s < 8; s++) v += red[s][b][cl];
    int c2 = strip * 64 + cl;
    if (slice == 0) v += hB[b * E + c2] + bias[c2];
    atomicAdd(&hA[b * E + c2], v);
  }
}

// ---- LNF + logits + exp + partial sums (grid 256) ----
__global__ __launch_bounds__(512) void k_logits(const float* __restrict__ hA,
    const float* __restrict__ lnfw, const float* __restrict__ lnfb,
    const float* __restrict__ wte, float* __restrict__ out,
    float* __restrict__ gsum) {
  __shared__ float smean[B], srstd[B];
  __shared__ float hp[B][E];
  __shared__ float ssum[B];
  int t = threadIdx.x, lane = t & 63;
  ln_stats512(hA, smean, srstd);
  if (t < B) ssum[t] = 0.f;
  __syncthreads();
  for (int i = t; i < B * E; i += 512) {
    int b = i >> 10, e = i & 1023;
    hp[b][e] = (hA[i] - smean[b]) * srstd[b] * lnfw[e] + lnfb[e];
  }
  __syncthreads();
  int pair = t >> 1, half = t & 1;
  int r = blockIdx.x + 256 * pair;           // row-interleaved across blocks
  bool active = (r < V);
  float p[8];
  if (active) {
    float acc[8] = {0.f};
    const float4* wrow = (const float4*)(wte + (size_t)r * E + half * 512);
    int e0 = half * 512;
    for (int i = 0; i < 128; i++) {
      float4 w = wrow[i];
      int e = e0 + i * 4;
#pragma unroll
      for (int b = 0; b < 8; b++)
        acc[b] += w.x * hp[b][e] + w.y * hp[b][e + 1] +
                  w.z * hp[b][e + 2] + w.w * hp[b][e + 3];
    }
#pragma unroll
    for (int b = 0; b < 8; b++) {
      float a = acc[b] + __shfl_xor(acc[b], 1);   // pair lanes both active
      p[b] = expf(a);
    }
    if (half == 0) {
#pragma unroll
      for (int b = 0; b < 8; b++) out[(size_t)b * V + r] = p[b];
    }
  }
#pragma unroll
  for (int b = 0; b < 8; b++) {
    float v = (active && half == 0) ? p[b] : 0.f;
#pragma unroll
    for (int o = 32; o; o >>= 1) v += __shfl_down(v, o);
    if (lane == 0) atomicAdd(&ssum[b], v);
  }
  __syncthreads();
  if (t < B) atomicAdd(&gsum[t], ssum[t]);
}

// ---- normalize ----
__global__ __launch_bounds__(256) void k_norm(float* __restrict__ out,
                                              const float* __restrict__ gsum) {
  int i = blockIdx.x * 256 + threadIdx.x;
  if (i < B * V) {
    int b = i / V;
    out[i] = out[i] / gsum[b];
  }
}

extern "C" void kernel_launch(void* const* d_in, const int* in_sizes, int n_in,
                              void* d_out, int out_size, void* d_ws, size_t ws_size,
                              hipStream_t stream) {
  const int*   ids = (const int*)d_in[0];
  const float* kc  = (const float*)d_in[1];
  const float* vc  = (const float*)d_in[2];
  const float* wte = (const float*)d_in[3];
  const float* wpe = (const float*)d_in[4];
  const float* l1w = (const float*)d_in[5];
  const float* l1b = (const float*)d_in[6];
  const float* caw = (const float*)d_in[7];
  const float* cab = (const float*)d_in[8];
  const float* apw = (const float*)d_in[9];
  const float* apb = (const float*)d_in[10];
  const float* l2w = (const float*)d_in[11];
  const float* l2b = (const float*)d_in[12];
  const float* fcw = (const float*)d_in[13];
  const float* fcb = (const float*)d_in[14];
  const float* pw  = (const float*)d_in[15];
  const float* pb  = (const float*)d_in[16];
  const float* lnfw = (const float*)d_in[17];
  const float* lnfb = (const float*)d_in[18];
  float* out = (float*)d_out;
  float* ws  = (float*)d_ws;

  float* hA   = ws + WS_HA;
  float* hB   = ws + WS_HB;
  float* qkv  = ws + WS_QKV;
  float* m1   = ws + WS_M1;
  float* pm   = ws + WS_PM;
  float* pl   = ws + WS_PL;
  float* pctx = ws + WS_PCTX;
  float* gsum = ws + WS_GSUM;

  k_embed<<<128, 256, 0, stream>>>(ids, wte, wpe, hA, hB, qkv, m1, gsum);
  for (int l = 0; l < L; l++) {
    k_qkv<<<384, 512, 0, stream>>>(hA, l1w + l * E, l1b + l * E,
        caw + (size_t)l * E * 3 * E, cab + (size_t)l * 3 * E, qkv, m1, hB);
    k_attn<<<1024, 512, 0, stream>>>(kc + (size_t)l * B * H * T * D,
        vc + (size_t)l * B * H * T * D, qkv, pm, pl, pctx);
    k_proj<<<256, 512, 0, stream>>>(hA, apw + (size_t)l * E * E, apb + (size_t)l * E,
        pm, pl, pctx, hB);
    k_fc<<<512, 512, 0, stream>>>(hB, l2w + l * E, l2b + l * E,
        fcw + (size_t)l * E * F, fcb + (size_t)l * F, m1, hA, qkv);
    k_mlp<<<512, 512, 0, stream>>>(m1, pw + (size_t)l * F * E, pb + (size_t)l * E,
        hB, hA);
  }
  k_logits<<<256, 512, 0, stream>>>(hA, lnfw, lnfb, wte, out, gsum);
  k_norm<<<(B * V + 255) / 256, 256, 0, stream>>>(out, gsum);
}